// Round 2
// baseline (661.562 us; speedup 1.0000x reference)
//
#include <hip/hip_runtime.h>

// Problem constants
#define B_   512
#define T_   128
#define D_   384
#define H_   6
#define DH_  64
#define DFF_ 1536
#define NROW (B_*T_)   // 65536 rows

typedef __attribute__((ext_vector_type(8))) short bf16x8;   // 8 bf16 = 4 VGPRs (MFMA A/B frag)
typedef __attribute__((ext_vector_type(4))) float f32x4;    // MFMA C/D frag

__device__ __forceinline__ unsigned short f2bf(float f) {
  union { float f; unsigned u; } v; v.f = f;
  unsigned r = v.u + 0x7fffu + ((v.u >> 16) & 1u);   // RNE
  return (unsigned short)(r >> 16);
}

// ---------------- weight transpose + fp32->bf16 convert ----------------
// W is [K][Nn] row-major fp32; WT becomes [Nn][K] row-major bf16 (i.e. B^T for NT GEMM)
__global__ void wt_kernel(const float* __restrict__ W, unsigned short* __restrict__ WT,
                          int K, int Nn) {
  int id = blockIdx.x * 256 + threadIdx.x;
  if (id >= K * Nn) return;
  int n = id % Nn, kk = id / Nn;               // coalesced read along n
  WT[(size_t)n * K + kk] = f2bf(W[(size_t)kk * Nn + n]);
}

// ---------------- layernorm: fp32 in -> bf16 out (one wave per row) ----------------
__global__ __launch_bounds__(256) void ln_kernel(const float* __restrict__ x,
                                                 const float* __restrict__ g,
                                                 const float* __restrict__ be,
                                                 unsigned short* __restrict__ out) {
  int row = (blockIdx.x * 256 + threadIdx.x) >> 6;
  int l = threadIdx.x & 63;
  const float* xr = x + (size_t)row * D_;
  float v[6]; float s = 0.f, ss = 0.f;
  #pragma unroll
  for (int i = 0; i < 6; ++i) { v[i] = xr[l + i*64]; s += v[i]; ss += v[i]*v[i]; }
  #pragma unroll
  for (int m = 1; m < 64; m <<= 1) { s += __shfl_xor(s, m); ss += __shfl_xor(ss, m); }
  float mu  = s * (1.f / D_);
  float var = ss * (1.f / D_) - mu * mu;
  float rs  = rsqrtf(var + 1e-5f);
  unsigned short* orow = out + (size_t)row * D_;
  #pragma unroll
  for (int i = 0; i < 6; ++i) {
    int c = l + i*64;
    orow[c] = f2bf((v[i] - mu) * rs * g[c] + be[c]);
  }
}

// ---------------- NT GEMM: C[M,Nn] = A[M,K](bf16) x BT[Nn,K](bf16)^T + epilogue ----------
// EPI 0: store bf16
// EPI 1: += bias[col] + res[row,col], store fp32
// EPI 2: += bias[col], relu, store bf16
template<int EPI>
__global__ __launch_bounds__(256) void gemm_bt(const unsigned short* __restrict__ A,
                                               const unsigned short* __restrict__ BT,
                                               void* __restrict__ Cc,
                                               const float* __restrict__ bias,
                                               const float* __restrict__ res,
                                               int Nn, int K) {
  __shared__ unsigned short As[128][40];   // +8 pad: 2-way bank aliasing only (free)
  __shared__ unsigned short Bs[128][40];
  int tid = threadIdx.x, w = tid >> 6, l = tid & 63;
  int wr = w >> 1, wc = w & 1;             // 2x2 waves over 128x128 tile, 64x64 each
  size_t R0 = (size_t)blockIdx.x * 128;
  int C0 = blockIdx.y * 128;

  f32x4 acc[4][4];
  #pragma unroll
  for (int i = 0; i < 4; ++i)
    #pragma unroll
    for (int j = 0; j < 4; ++j) acc[i][j] = (f32x4){0.f, 0.f, 0.f, 0.f};

  for (int k0 = 0; k0 < K; k0 += 32) {
    #pragma unroll
    for (int p = 0; p < 2; ++p) {
      int id = p * 256 + tid;
      int r = id >> 2, c8 = (id & 3) * 8;
      *(int4*)(&As[r][c8]) = *(const int4*)(A  + (R0 + r) * K + k0 + c8);
      *(int4*)(&Bs[r][c8]) = *(const int4*)(BT + (size_t)(C0 + r) * K + k0 + c8);
    }
    __syncthreads();
    bf16x8 af[4], bf[4];
    #pragma unroll
    for (int mi = 0; mi < 4; ++mi)
      af[mi] = *(const bf16x8*)(&As[wr*64 + mi*16 + (l & 15)][(l >> 4) * 8]);
    #pragma unroll
    for (int ni = 0; ni < 4; ++ni)
      bf[ni] = *(const bf16x8*)(&Bs[wc*64 + ni*16 + (l & 15)][(l >> 4) * 8]);
    #pragma unroll
    for (int mi = 0; mi < 4; ++mi)
      #pragma unroll
      for (int ni = 0; ni < 4; ++ni)
        acc[mi][ni] = __builtin_amdgcn_mfma_f32_16x16x32_bf16(af[mi], bf[ni], acc[mi][ni], 0, 0, 0);
    __syncthreads();
  }

  #pragma unroll
  for (int mi = 0; mi < 4; ++mi) {
    #pragma unroll
    for (int ni = 0; ni < 4; ++ni) {
      int col = C0 + wc*64 + ni*16 + (l & 15);
      #pragma unroll
      for (int j = 0; j < 4; ++j) {
        size_t row = R0 + wr*64 + mi*16 + ((l >> 4) << 2) + j;
        float vv = acc[mi][ni][j];
        if (EPI == 0) {
          ((unsigned short*)Cc)[row * Nn + col] = f2bf(vv);
        } else if (EPI == 1) {
          ((float*)Cc)[row * Nn + col] = vv + bias[col] + res[row * Nn + col];
        } else {
          vv += bias[col];
          ((unsigned short*)Cc)[row * Nn + col] = f2bf(vv > 0.f ? vv : 0.f);
        }
      }
    }
  }
}

// ---------------- causal attention, one block per (b,h), T=128, DH=64 ----------------
// LDS union keeps static shared < 64 KB:
//   phase 1: Ks [128][72] (18432 B) at offset 0
//   phase 2: Ps [4][32][136] (34816 B) at offset 0   (K dead after QK^T; barrier in between)
//   always : Vt [64][136]  (17408 B) at offset 34816
// total 52224 B
__global__ __launch_bounds__(256) void attn_kernel(const unsigned short* __restrict__ q,
                                                   const unsigned short* __restrict__ k,
                                                   const unsigned short* __restrict__ v,
                                                   unsigned short* __restrict__ o) {
  __shared__ __align__(16) char smem[52224];
  unsigned short (*Ks)[72]       = (unsigned short(*)[72])smem;
  unsigned short (*Ps)[32][136]  = (unsigned short(*)[32][136])smem;
  unsigned short (*Vt)[136]      = (unsigned short(*)[136])(smem + 34816);

  int bh = blockIdx.x;
  int b = bh / H_, h = bh % H_;
  int tid = threadIdx.x, w = tid >> 6, l = tid & 63;

  const unsigned short* kb = k + ((size_t)b * T_) * D_ + h * DH_;
  const unsigned short* vb = v + ((size_t)b * T_) * D_ + h * DH_;
  #pragma unroll
  for (int it = 0; it < 4; ++it) {
    int id = it * 256 + tid;
    int s = id >> 3, c8 = (id & 7) * 8;
    int4 kv = *(const int4*)(kb + (size_t)s * D_ + c8);
    *(int4*)(&Ks[s][c8]) = kv;
    int4 vv = *(const int4*)(vb + (size_t)s * D_ + c8);
    const unsigned short* pe = (const unsigned short*)&vv;
    #pragma unroll
    for (int j2 = 0; j2 < 8; ++j2) Vt[c8 + j2][s] = pe[j2];
  }
  __syncthreads();

  // Q fragments straight from global (each wave owns rows w*32..w*32+31)
  const unsigned short* qbp = q + ((size_t)b * T_) * D_ + h * DH_;
  int rowbase = w * 32;
  bf16x8 aq[2][2];
  #pragma unroll
  for (int mi = 0; mi < 2; ++mi)
    #pragma unroll
    for (int ks = 0; ks < 2; ++ks)
      aq[mi][ks] = *(const bf16x8*)(qbp + (size_t)(rowbase + mi*16 + (l & 15)) * D_
                                        + ks*32 + ((l >> 4) << 3));

  // S = Q K^T  (wave strip: 32 x 128)
  f32x4 accs[2][8];
  #pragma unroll
  for (int i = 0; i < 2; ++i)
    #pragma unroll
    for (int j = 0; j < 8; ++j) accs[i][j] = (f32x4){0.f, 0.f, 0.f, 0.f};
  #pragma unroll
  for (int ks = 0; ks < 2; ++ks) {
    bf16x8 bk[8];
    #pragma unroll
    for (int ni = 0; ni < 8; ++ni)
      bk[ni] = *(const bf16x8*)(&Ks[ni*16 + (l & 15)][ks*32 + ((l >> 4) << 3)]);
    #pragma unroll
    for (int mi = 0; mi < 2; ++mi)
      #pragma unroll
      for (int ni = 0; ni < 8; ++ni)
        accs[mi][ni] = __builtin_amdgcn_mfma_f32_16x16x32_bf16(aq[mi][ks], bk[ni], accs[mi][ni], 0, 0, 0);
  }
  __syncthreads();   // all waves done reading Ks before P overwrites it

  // causal mask + row softmax (full row lives in 16 lanes x 8 ni-regs)
  #pragma unroll
  for (int mi = 0; mi < 2; ++mi) {
    #pragma unroll
    for (int j = 0; j < 4; ++j) {
      int t = rowbase + mi*16 + ((l >> 4) << 2) + j;
      float mx = -1e30f;
      #pragma unroll
      for (int ni = 0; ni < 8; ++ni) {
        int scol = ni*16 + (l & 15);
        float sv = accs[mi][ni][j] * 0.125f;
        sv = (scol <= t) ? sv : -1e30f;
        accs[mi][ni][j] = sv;
        mx = fmaxf(mx, sv);
      }
      mx = fmaxf(mx, __shfl_xor(mx, 1));
      mx = fmaxf(mx, __shfl_xor(mx, 2));
      mx = fmaxf(mx, __shfl_xor(mx, 4));
      mx = fmaxf(mx, __shfl_xor(mx, 8));
      float sum = 0.f;
      #pragma unroll
      for (int ni = 0; ni < 8; ++ni) {
        float e = __expf(accs[mi][ni][j] - mx);
        accs[mi][ni][j] = e;
        sum += e;
      }
      sum += __shfl_xor(sum, 1);
      sum += __shfl_xor(sum, 2);
      sum += __shfl_xor(sum, 4);
      sum += __shfl_xor(sum, 8);
      float inv = 1.f / sum;
      #pragma unroll
      for (int ni = 0; ni < 8; ++ni)
        Ps[w][mi*16 + ((l >> 4) << 2) + j][ni*16 + (l & 15)] = f2bf(accs[mi][ni][j] * inv);
    }
  }
  __syncthreads();

  // O = P V   (NT against Vt)
  f32x4 acco[2][4];
  #pragma unroll
  for (int i = 0; i < 2; ++i)
    #pragma unroll
    for (int j = 0; j < 4; ++j) acco[i][j] = (f32x4){0.f, 0.f, 0.f, 0.f};
  #pragma unroll
  for (int ks = 0; ks < 4; ++ks) {
    bf16x8 ap[2], bv[4];
    #pragma unroll
    for (int mi = 0; mi < 2; ++mi)
      ap[mi] = *(const bf16x8*)(&Ps[w][mi*16 + (l & 15)][ks*32 + ((l >> 4) << 3)]);
    #pragma unroll
    for (int ni = 0; ni < 4; ++ni)
      bv[ni] = *(const bf16x8*)(&Vt[ni*16 + (l & 15)][ks*32 + ((l >> 4) << 3)]);
    #pragma unroll
    for (int mi = 0; mi < 2; ++mi)
      #pragma unroll
      for (int ni = 0; ni < 4; ++ni)
        acco[mi][ni] = __builtin_amdgcn_mfma_f32_16x16x32_bf16(ap[mi], bv[ni], acco[mi][ni], 0, 0, 0);
  }

  unsigned short* ob = o + ((size_t)b * T_) * D_ + h * DH_;
  #pragma unroll
  for (int mi = 0; mi < 2; ++mi)
    #pragma unroll
    for (int ni = 0; ni < 4; ++ni)
      #pragma unroll
      for (int j = 0; j < 4; ++j) {
        int t = rowbase + mi*16 + ((l >> 4) << 2) + j;
        int d = ni*16 + (l & 15);
        ob[(size_t)t * D_ + d] = f2bf(acco[mi][ni][j]);
      }
}

extern "C" void kernel_launch(void* const* d_in, const int* in_sizes, int n_in,
                              void* d_out, int out_size, void* d_ws, size_t ws_size,
                              hipStream_t stream) {
  const float* x   = (const float*)d_in[0];
  const float* Wq  = (const float*)d_in[1];
  const float* Wk  = (const float*)d_in[2];
  const float* Wv  = (const float*)d_in[3];
  const float* Wo  = (const float*)d_in[4];
  const float* bo  = (const float*)d_in[5];
  const float* W1  = (const float*)d_in[6];
  const float* b1  = (const float*)d_in[7];
  const float* W2  = (const float*)d_in[8];
  const float* b2  = (const float*)d_in[9];
  const float* g1  = (const float*)d_in[10];
  const float* be1 = (const float*)d_in[11];
  const float* g2  = (const float*)d_in[12];
  const float* be2 = (const float*)d_in[13];

  // workspace layout (bytes); total ~195 MiB
  //   hb   [65536][384]  bf16  50,331,648  : h (LN1 out), later h2 (LN2 out)
  //   qb   [65536][384]  bf16  50,331,648  : q, overwritten in-place by attention output o
  //   kbuf [65536][384]  bf16  50,331,648  : k; dead after attn -> ff chunk buffer (with vbuf)
  //   vbuf [65536][384]  bf16  50,331,648  : v; dead after attn
  //   weights (bf16 transposed)             3,538,944
  // x2 (fp32 residual stream) lives in d_out.
  char* ws = (char*)d_ws;
  unsigned short* hb   = (unsigned short*)(ws);
  unsigned short* qb   = (unsigned short*)(ws +  50331648);
  unsigned short* kbuf = (unsigned short*)(ws + 100663296);
  unsigned short* vbuf = (unsigned short*)(ws + 150994944);
  unsigned short* ffb  = kbuf;   // [32768][1536] bf16 = 100,663,296 B spans kbuf+vbuf
  unsigned short* wqT  = (unsigned short*)(ws + 201326592);
  unsigned short* wkT  = wqT + 147456;
  unsigned short* wvT  = wkT + 147456;
  unsigned short* woT  = wvT + 147456;
  unsigned short* w1T  = woT + 147456;                       // [1536][384]
  unsigned short* w2T  = w1T + 589824;                       // [384][1536]
  float* x2 = (float*)d_out;

  // 1) weight convert+transpose (tiny)
  wt_kernel<<<dim3((384*384 + 255) / 256), 256, 0, stream>>>(Wq, wqT, 384, 384);
  wt_kernel<<<dim3((384*384 + 255) / 256), 256, 0, stream>>>(Wk, wkT, 384, 384);
  wt_kernel<<<dim3((384*384 + 255) / 256), 256, 0, stream>>>(Wv, wvT, 384, 384);
  wt_kernel<<<dim3((384*384 + 255) / 256), 256, 0, stream>>>(Wo, woT, 384, 384);
  wt_kernel<<<dim3((384*1536 + 255) / 256), 256, 0, stream>>>(W1, w1T, 384, 1536);
  wt_kernel<<<dim3((1536*384 + 255) / 256), 256, 0, stream>>>(W2, w2T, 1536, 384);

  // 2) LN1: x -> h (bf16)
  ln_kernel<<<dim3(NROW / 4), 256, 0, stream>>>(x, g1, be1, hb);

  // 3) q,k,v = h @ W{q,k,v}
  dim3 g3(NROW / 128, 3);
  gemm_bt<0><<<g3, 256, 0, stream>>>(hb, wqT, qb,   nullptr, nullptr, 384, 384);
  gemm_bt<0><<<g3, 256, 0, stream>>>(hb, wkT, kbuf, nullptr, nullptr, 384, 384);
  gemm_bt<0><<<g3, 256, 0, stream>>>(hb, wvT, vbuf, nullptr, nullptr, 384, 384);

  // 4) attention: o overwrites q in place (per-block disjoint strips)
  attn_kernel<<<dim3(B_ * H_), 256, 0, stream>>>(qb, kbuf, vbuf, qb);

  // 5) x2 = x + o @ Wo + bo   (fp32, into d_out)
  gemm_bt<1><<<g3, 256, 0, stream>>>(qb, woT, x2, bo, x, 384, 384);

  // 6) LN2: x2 -> h2 (bf16, into hb)
  ln_kernel<<<dim3(NROW / 4), 256, 0, stream>>>((const float*)x2, g2, be2, hb);

  // 7) FFN in 2 row-chunks of 32768 (ffb reuses dead k/v region)
  for (int c = 0; c < 2; ++c) {
    const unsigned short* h2c = hb + (size_t)c * 32768 * 384;
    float* outc = x2 + (size_t)c * 32768 * 384;
    gemm_bt<2><<<dim3(256, 12), 256, 0, stream>>>(h2c, w1T, ffb, b1, nullptr, 1536, 384);
    gemm_bt<1><<<dim3(256, 3),  256, 0, stream>>>(ffb, w2T, outc, b2, outc, 384, 1536);
  }
}

// Round 3
// 652.460 us; speedup vs baseline: 1.0140x; 1.0140x over previous
//
#include <hip/hip_runtime.h>

// Problem constants
#define B_   512
#define T_   128
#define D_   384
#define H_   6
#define DH_  64
#define DFF_ 1536
#define NROW (B_*T_)   // 65536 rows

typedef __attribute__((ext_vector_type(8))) short bf16x8;   // 8 bf16 = 4 VGPRs (MFMA A/B frag)
typedef __attribute__((ext_vector_type(4))) float f32x4;    // MFMA C/D frag

__device__ __forceinline__ unsigned short f2bf(float f) {
  union { float f; unsigned u; } v; v.f = f;
  unsigned r = v.u + 0x7fffu + ((v.u >> 16) & 1u);   // RNE
  return (unsigned short)(r >> 16);
}

// async global->LDS, 16 B per lane, wave-uniform LDS base (m97 pattern)
#define GLDS16(gp, lp)                                                     \
  __builtin_amdgcn_global_load_lds(                                        \
      (const __attribute__((address_space(1))) void*)(gp),                 \
      (__attribute__((address_space(3))) void*)(lp), 16, 0, 0)

// ---------------- weight transpose + fp32->bf16 convert ----------------
// W is [K][Nn] row-major fp32; WT becomes [Nn][K] row-major bf16 (i.e. B^T for NT GEMM)
__global__ void wt_kernel(const float* __restrict__ W, unsigned short* __restrict__ WT,
                          int K, int Nn) {
  int id = blockIdx.x * 256 + threadIdx.x;
  if (id >= K * Nn) return;
  int n = id % Nn, kk = id / Nn;               // coalesced read along n
  WT[(size_t)n * K + kk] = f2bf(W[(size_t)kk * Nn + n]);
}

// ---------------- layernorm: fp32 in -> bf16 out (one wave per row) ----------------
__global__ __launch_bounds__(256) void ln_kernel(const float* __restrict__ x,
                                                 const float* __restrict__ g,
                                                 const float* __restrict__ be,
                                                 unsigned short* __restrict__ out) {
  int row = (blockIdx.x * 256 + threadIdx.x) >> 6;
  int l = threadIdx.x & 63;
  const float* xr = x + (size_t)row * D_;
  float v[6]; float s = 0.f, ss = 0.f;
  #pragma unroll
  for (int i = 0; i < 6; ++i) { v[i] = xr[l + i*64]; s += v[i]; ss += v[i]*v[i]; }
  #pragma unroll
  for (int m = 1; m < 64; m <<= 1) { s += __shfl_xor(s, m); ss += __shfl_xor(ss, m); }
  float mu  = s * (1.f / D_);
  float var = ss * (1.f / D_) - mu * mu;
  float rs  = rsqrtf(var + 1e-5f);
  unsigned short* orow = out + (size_t)row * D_;
  #pragma unroll
  for (int i = 0; i < 6; ++i) {
    int c = l + i*64;
    orow[c] = f2bf((v[i] - mu) * rs * g[c] + be[c]);
  }
}

// ---------------- NT GEMM: C[M,Nn] = A[M,K](bf16) x BT[Nn,K](bf16)^T + epilogue ----------
// EPI 0: store bf16
// EPI 1: += bias[col] + res[row,col], store fp32
// EPI 2: += bias[col], relu, store bf16
// EPI 3: store bf16 split across 3 contiguous [NROW,384] buffers (fused QKV)
template<int EPI>
__global__ __launch_bounds__(256) void gemm_bt(const unsigned short* __restrict__ A,
                                               const unsigned short* __restrict__ BT,
                                               void* __restrict__ Cc,
                                               const float* __restrict__ bias,
                                               const float* __restrict__ res,
                                               int Nn, int K) {
  __shared__ unsigned short As[128][32];   // linear: required by global_load_lds
  __shared__ unsigned short Bs[128][32];
  int tid = threadIdx.x, w = tid >> 6, l = tid & 63;
  int wr = w >> 1, wc = w & 1;             // 2x2 waves over 128x128 tile, 64x64 each
  size_t R0 = (size_t)blockIdx.x * 128;
  int C0 = blockIdx.y * 128;

  // staging geometry: wave w, issue p covers LDS rows (w*2+p)*16 .. +16
  // lane l -> row +(l>>2), col8 = (l&3)*8
  int seg0 = (w * 2 + 0) * 16;
  int seg1 = (w * 2 + 1) * 16;
  int srow0 = seg0 + (l >> 2);
  int srow1 = seg1 + (l >> 2);
  int scol  = (l & 3) * 8;

  const unsigned short* ga0 = A  + (R0 + srow0) * K + scol;
  const unsigned short* ga1 = A  + (R0 + srow1) * K + scol;
  const unsigned short* gb0 = BT + (size_t)(C0 + srow0) * K + scol;
  const unsigned short* gb1 = BT + (size_t)(C0 + srow1) * K + scol;

  f32x4 acc[4][4];
  #pragma unroll
  for (int i = 0; i < 4; ++i)
    #pragma unroll
    for (int j = 0; j < 4; ++j) acc[i][j] = (f32x4){0.f, 0.f, 0.f, 0.f};

  for (int k0 = 0; k0 < K; k0 += 32) {
    GLDS16(ga0, &As[seg0][0]);
    GLDS16(ga1, &As[seg1][0]);
    GLDS16(gb0, &Bs[seg0][0]);
    GLDS16(gb1, &Bs[seg1][0]);
    ga0 += 32; ga1 += 32; gb0 += 32; gb1 += 32;
    __syncthreads();   // compiler emits vmcnt(0) drain before barrier

    bf16x8 af[4], bf[4];
    #pragma unroll
    for (int mi = 0; mi < 4; ++mi)
      af[mi] = *(const bf16x8*)(&As[wr*64 + mi*16 + (l & 15)][(l >> 4) * 8]);
    #pragma unroll
    for (int ni = 0; ni < 4; ++ni)
      bf[ni] = *(const bf16x8*)(&Bs[wc*64 + ni*16 + (l & 15)][(l >> 4) * 8]);
    #pragma unroll
    for (int mi = 0; mi < 4; ++mi)
      #pragma unroll
      for (int ni = 0; ni < 4; ++ni)
        acc[mi][ni] = __builtin_amdgcn_mfma_f32_16x16x32_bf16(af[mi], bf[ni], acc[mi][ni], 0, 0, 0);
    __syncthreads();
  }

  #pragma unroll
  for (int mi = 0; mi < 4; ++mi) {
    #pragma unroll
    for (int ni = 0; ni < 4; ++ni) {
      int col = C0 + wc*64 + ni*16 + (l & 15);
      #pragma unroll
      for (int j = 0; j < 4; ++j) {
        size_t row = R0 + wr*64 + mi*16 + ((l >> 4) << 2) + j;
        float vv = acc[mi][ni][j];
        if (EPI == 0) {
          ((unsigned short*)Cc)[row * Nn + col] = f2bf(vv);
        } else if (EPI == 1) {
          ((float*)Cc)[row * Nn + col] = vv + bias[col] + res[row * Nn + col];
        } else if (EPI == 2) {
          vv += bias[col];
          ((unsigned short*)Cc)[row * Nn + col] = f2bf(vv > 0.f ? vv : 0.f);
        } else {
          int buf = col / 384, c2 = col - buf * 384;   // buf uniform per block (128 | 384*k)
          ((unsigned short*)Cc)[(size_t)buf * NROW * 384 + row * 384 + c2] = f2bf(vv);
        }
      }
    }
  }
}

// ---------------- causal attention, one block per (b,h), T=128, DH=64 ----------------
// LDS union keeps static shared < 64 KB:
//   phase 1: Ks [128][72] (18432 B) at offset 0
//   phase 2: Ps [4][32][136] (34816 B) at offset 0   (K dead after QK^T; barrier in between)
//   always : Vt [64][136]  (17408 B) at offset 34816
// total 52224 B
__global__ __launch_bounds__(256) void attn_kernel(const unsigned short* __restrict__ q,
                                                   const unsigned short* __restrict__ k,
                                                   const unsigned short* __restrict__ v,
                                                   unsigned short* __restrict__ o) {
  __shared__ __align__(16) char smem[52224];
  unsigned short (*Ks)[72]       = (unsigned short(*)[72])smem;
  unsigned short (*Ps)[32][136]  = (unsigned short(*)[32][136])smem;
  unsigned short (*Vt)[136]      = (unsigned short(*)[136])(smem + 34816);

  int bh = blockIdx.x;
  int b = bh / H_, h = bh % H_;
  int tid = threadIdx.x, w = tid >> 6, l = tid & 63;

  const unsigned short* kb = k + ((size_t)b * T_) * D_ + h * DH_;
  const unsigned short* vb = v + ((size_t)b * T_) * D_ + h * DH_;
  #pragma unroll
  for (int it = 0; it < 4; ++it) {
    int id = it * 256 + tid;
    int s = id >> 3, c8 = (id & 7) * 8;
    int4 kv = *(const int4*)(kb + (size_t)s * D_ + c8);
    *(int4*)(&Ks[s][c8]) = kv;
    int4 vv = *(const int4*)(vb + (size_t)s * D_ + c8);
    const unsigned short* pe = (const unsigned short*)&vv;
    #pragma unroll
    for (int j2 = 0; j2 < 8; ++j2) Vt[c8 + j2][s] = pe[j2];
  }
  __syncthreads();

  // Q fragments straight from global (each wave owns rows w*32..w*32+31)
  const unsigned short* qbp = q + ((size_t)b * T_) * D_ + h * DH_;
  int rowbase = w * 32;
  bf16x8 aq[2][2];
  #pragma unroll
  for (int mi = 0; mi < 2; ++mi)
    #pragma unroll
    for (int ks = 0; ks < 2; ++ks)
      aq[mi][ks] = *(const bf16x8*)(qbp + (size_t)(rowbase + mi*16 + (l & 15)) * D_
                                        + ks*32 + ((l >> 4) << 3));

  // S = Q K^T  (wave strip: 32 x 128)
  f32x4 accs[2][8];
  #pragma unroll
  for (int i = 0; i < 2; ++i)
    #pragma unroll
    for (int j = 0; j < 8; ++j) accs[i][j] = (f32x4){0.f, 0.f, 0.f, 0.f};
  #pragma unroll
  for (int ks = 0; ks < 2; ++ks) {
    bf16x8 bk[8];
    #pragma unroll
    for (int ni = 0; ni < 8; ++ni)
      bk[ni] = *(const bf16x8*)(&Ks[ni*16 + (l & 15)][ks*32 + ((l >> 4) << 3)]);
    #pragma unroll
    for (int mi = 0; mi < 2; ++mi)
      #pragma unroll
      for (int ni = 0; ni < 8; ++ni)
        accs[mi][ni] = __builtin_amdgcn_mfma_f32_16x16x32_bf16(aq[mi][ks], bk[ni], accs[mi][ni], 0, 0, 0);
  }
  __syncthreads();   // all waves done reading Ks before P overwrites it

  // causal mask + row softmax (full row lives in 16 lanes x 8 ni-regs)
  #pragma unroll
  for (int mi = 0; mi < 2; ++mi) {
    #pragma unroll
    for (int j = 0; j < 4; ++j) {
      int t = rowbase + mi*16 + ((l >> 4) << 2) + j;
      float mx = -1e30f;
      #pragma unroll
      for (int ni = 0; ni < 8; ++ni) {
        int scol = ni*16 + (l & 15);
        float sv = accs[mi][ni][j] * 0.125f;
        sv = (scol <= t) ? sv : -1e30f;
        accs[mi][ni][j] = sv;
        mx = fmaxf(mx, sv);
      }
      mx = fmaxf(mx, __shfl_xor(mx, 1));
      mx = fmaxf(mx, __shfl_xor(mx, 2));
      mx = fmaxf(mx, __shfl_xor(mx, 4));
      mx = fmaxf(mx, __shfl_xor(mx, 8));
      float sum = 0.f;
      #pragma unroll
      for (int ni = 0; ni < 8; ++ni) {
        float e = __expf(accs[mi][ni][j] - mx);
        accs[mi][ni][j] = e;
        sum += e;
      }
      sum += __shfl_xor(sum, 1);
      sum += __shfl_xor(sum, 2);
      sum += __shfl_xor(sum, 4);
      sum += __shfl_xor(sum, 8);
      float inv = 1.f / sum;
      #pragma unroll
      for (int ni = 0; ni < 8; ++ni)
        Ps[w][mi*16 + ((l >> 4) << 2) + j][ni*16 + (l & 15)] = f2bf(accs[mi][ni][j] * inv);
    }
  }
  __syncthreads();

  // O = P V   (NT against Vt)
  f32x4 acco[2][4];
  #pragma unroll
  for (int i = 0; i < 2; ++i)
    #pragma unroll
    for (int j = 0; j < 4; ++j) acco[i][j] = (f32x4){0.f, 0.f, 0.f, 0.f};
  #pragma unroll
  for (int ks = 0; ks < 4; ++ks) {
    bf16x8 ap[2], bv[4];
    #pragma unroll
    for (int mi = 0; mi < 2; ++mi)
      ap[mi] = *(const bf16x8*)(&Ps[w][mi*16 + (l & 15)][ks*32 + ((l >> 4) << 3)]);
    #pragma unroll
    for (int ni = 0; ni < 4; ++ni)
      bv[ni] = *(const bf16x8*)(&Vt[ni*16 + (l & 15)][ks*32 + ((l >> 4) << 3)]);
    #pragma unroll
    for (int mi = 0; mi < 2; ++mi)
      #pragma unroll
      for (int ni = 0; ni < 4; ++ni)
        acco[mi][ni] = __builtin_amdgcn_mfma_f32_16x16x32_bf16(ap[mi], bv[ni], acco[mi][ni], 0, 0, 0);
  }

  unsigned short* ob = o + ((size_t)b * T_) * D_ + h * DH_;
  #pragma unroll
  for (int mi = 0; mi < 2; ++mi)
    #pragma unroll
    for (int ni = 0; ni < 4; ++ni)
      #pragma unroll
      for (int j = 0; j < 4; ++j) {
        int t = rowbase + mi*16 + ((l >> 4) << 2) + j;
        int d = ni*16 + (l & 15);
        ob[(size_t)t * D_ + d] = f2bf(acco[mi][ni][j]);
      }
}

extern "C" void kernel_launch(void* const* d_in, const int* in_sizes, int n_in,
                              void* d_out, int out_size, void* d_ws, size_t ws_size,
                              hipStream_t stream) {
  const float* x   = (const float*)d_in[0];
  const float* Wq  = (const float*)d_in[1];
  const float* Wk  = (const float*)d_in[2];
  const float* Wv  = (const float*)d_in[3];
  const float* Wo  = (const float*)d_in[4];
  const float* bo  = (const float*)d_in[5];
  const float* W1  = (const float*)d_in[6];
  const float* b1  = (const float*)d_in[7];
  const float* W2  = (const float*)d_in[8];
  const float* b2  = (const float*)d_in[9];
  const float* g1  = (const float*)d_in[10];
  const float* be1 = (const float*)d_in[11];
  const float* g2  = (const float*)d_in[12];
  const float* be2 = (const float*)d_in[13];

  // workspace layout (bytes); total ~195 MiB
  //   hb   [65536][384]  bf16  50,331,648  : h (LN1 out), later h2 (LN2 out)
  //   qb   [65536][384]  bf16  50,331,648  : q, overwritten in-place by attention output o
  //   kbuf [65536][384]  bf16  50,331,648  : k; dead after attn -> ff chunk buffer (with vbuf)
  //   vbuf [65536][384]  bf16  50,331,648  : v; dead after attn
  //   weights (bf16 transposed, contiguous: wq|wk|wv forms [1152][384])
  // x2 (fp32 residual stream) lives in d_out.
  char* ws = (char*)d_ws;
  unsigned short* hb   = (unsigned short*)(ws);
  unsigned short* qb   = (unsigned short*)(ws +  50331648);   // q|k|v contiguous
  unsigned short* kbuf = (unsigned short*)(ws + 100663296);
  unsigned short* vbuf = (unsigned short*)(ws + 150994944);
  unsigned short* ffb  = kbuf;   // [32768][1536] bf16 = 100,663,296 B spans kbuf+vbuf
  unsigned short* wqT  = (unsigned short*)(ws + 201326592);
  unsigned short* wkT  = wqT + 147456;
  unsigned short* wvT  = wkT + 147456;
  unsigned short* woT  = wvT + 147456;
  unsigned short* w1T  = woT + 147456;                       // [1536][384]
  unsigned short* w2T  = w1T + 589824;                       // [384][1536]
  float* x2 = (float*)d_out;

  // 1) weight convert+transpose (tiny)
  wt_kernel<<<dim3((384*384 + 255) / 256), 256, 0, stream>>>(Wq, wqT, 384, 384);
  wt_kernel<<<dim3((384*384 + 255) / 256), 256, 0, stream>>>(Wk, wkT, 384, 384);
  wt_kernel<<<dim3((384*384 + 255) / 256), 256, 0, stream>>>(Wv, wvT, 384, 384);
  wt_kernel<<<dim3((384*384 + 255) / 256), 256, 0, stream>>>(Wo, woT, 384, 384);
  wt_kernel<<<dim3((384*1536 + 255) / 256), 256, 0, stream>>>(W1, w1T, 384, 1536);
  wt_kernel<<<dim3((1536*384 + 255) / 256), 256, 0, stream>>>(W2, w2T, 1536, 384);

  // 2) LN1: x -> h (bf16)
  ln_kernel<<<dim3(NROW / 4), 256, 0, stream>>>(x, g1, be1, hb);

  // 3) fused q|k|v = h @ [Wq|Wk|Wv]  (N=1152, split-store epilogue)
  gemm_bt<3><<<dim3(NROW / 128, 9), 256, 0, stream>>>(hb, wqT, qb, nullptr, nullptr, 1152, 384);

  // 4) attention: o overwrites q in place (per-block disjoint strips)
  attn_kernel<<<dim3(B_ * H_), 256, 0, stream>>>(qb, kbuf, vbuf, qb);

  // 5) x2 = x + o @ Wo + bo   (fp32, into d_out)
  gemm_bt<1><<<dim3(NROW / 128, 3), 256, 0, stream>>>(qb, woT, x2, bo, x, 384, 384);

  // 6) LN2: x2 -> h2 (bf16, into hb)
  ln_kernel<<<dim3(NROW / 4), 256, 0, stream>>>((const float*)x2, g2, be2, hb);

  // 7) FFN in 2 row-chunks of 32768 (ffb reuses dead k/v region)
  for (int c = 0; c < 2; ++c) {
    const unsigned short* h2c = hb + (size_t)c * 32768 * 384;
    float* outc = x2 + (size_t)c * 32768 * 384;
    gemm_bt<2><<<dim3(256, 12), 256, 0, stream>>>(h2c, w1T, ffb, b1, nullptr, 1536, 384);
    gemm_bt<1><<<dim3(256, 3),  256, 0, stream>>>(ffb, w2T, outc, b2, outc, 384, 1536);
  }
}

// Round 4
// 626.862 us; speedup vs baseline: 1.0554x; 1.0408x over previous
//
#include <hip/hip_runtime.h>

// Problem constants
#define B_   512
#define T_   128
#define D_   384
#define H_   6
#define DH_  64
#define DFF_ 1536
#define NROW (B_*T_)   // 65536 rows

typedef __attribute__((ext_vector_type(8))) short bf16x8;   // 8 bf16 = 4 VGPRs (MFMA A/B frag)
typedef __attribute__((ext_vector_type(4))) float f32x4;    // MFMA C/D frag

__device__ __forceinline__ unsigned short f2bf(float f) {
  union { float f; unsigned u; } v; v.f = f;
  unsigned r = v.u + 0x7fffu + ((v.u >> 16) & 1u);   // RNE
  return (unsigned short)(r >> 16);
}

// async global->LDS, 16 B per lane, wave-uniform LDS base (m97 pattern)
#define GLDS16(gp, lp)                                                     \
  __builtin_amdgcn_global_load_lds(                                        \
      (const __attribute__((address_space(1))) void*)(gp),                 \
      (__attribute__((address_space(3))) void*)(lp), 16, 0, 0)

// ---------------- weight transpose + fp32->bf16 convert ----------------
// W is [K][Nn] row-major fp32; WT becomes [Nn][K] row-major bf16 (i.e. B^T for NT GEMM)
__global__ void wt_kernel(const float* __restrict__ W, unsigned short* __restrict__ WT,
                          int K, int Nn) {
  int id = blockIdx.x * 256 + threadIdx.x;
  if (id >= K * Nn) return;
  int n = id % Nn, kk = id / Nn;               // coalesced read along n
  WT[(size_t)n * K + kk] = f2bf(W[(size_t)kk * Nn + n]);
}

// ---------------- layernorm: fp32 in -> bf16 out (one wave per row) ----------------
__global__ __launch_bounds__(256) void ln_kernel(const float* __restrict__ x,
                                                 const float* __restrict__ g,
                                                 const float* __restrict__ be,
                                                 unsigned short* __restrict__ out) {
  int row = (blockIdx.x * 256 + threadIdx.x) >> 6;
  int l = threadIdx.x & 63;
  const float* xr = x + (size_t)row * D_;
  float v[6]; float s = 0.f, ss = 0.f;
  #pragma unroll
  for (int i = 0; i < 6; ++i) { v[i] = xr[l + i*64]; s += v[i]; ss += v[i]*v[i]; }
  #pragma unroll
  for (int m = 1; m < 64; m <<= 1) { s += __shfl_xor(s, m); ss += __shfl_xor(ss, m); }
  float mu  = s * (1.f / D_);
  float var = ss * (1.f / D_) - mu * mu;
  float rs  = rsqrtf(var + 1e-5f);
  unsigned short* orow = out + (size_t)row * D_;
  #pragma unroll
  for (int i = 0; i < 6; ++i) {
    int c = l + i*64;
    orow[c] = f2bf((v[i] - mu) * rs * g[c] + be[c]);
  }
}

// ---------------- NT GEMM: C[M,Nn] = A[M,K](bf16) x BT[Nn,K](bf16)^T + epilogue ----------
// T3-minimal 2-phase double-buffered pipeline:
//   prologue: stage tile 0 -> buf0
//   iter t  : barrier (vmcnt(0)+lgkmcnt(0) drain: tile t landed, prior reads done)
//             issue stage(t+1) -> buf^1   (covers HBM/L3 latency under compute)
//             ds_read + 16x MFMA on buf[t&1]
// EPI 0: store bf16
// EPI 1: += bias[col] + res[row,col], store fp32
// EPI 2: += bias[col], relu, store bf16
// EPI 3: store bf16 split across 3 contiguous [NROW,384] buffers (fused QKV)
template<int EPI>
__global__ __launch_bounds__(256) void gemm_bt(const unsigned short* __restrict__ A,
                                               const unsigned short* __restrict__ BT,
                                               void* __restrict__ Cc,
                                               const float* __restrict__ bias,
                                               const float* __restrict__ res,
                                               int Nn, int K) {
  __shared__ unsigned short As[2][128][32];   // linear inner layout: required by global_load_lds
  __shared__ unsigned short Bs[2][128][32];
  int tid = threadIdx.x, w = tid >> 6, l = tid & 63;
  int wr = w >> 1, wc = w & 1;             // 2x2 waves over 128x128 tile, 64x64 each
  size_t R0 = (size_t)blockIdx.x * 128;
  int C0 = blockIdx.y * 128;

  // staging geometry: wave w issue p covers LDS rows (w*2+p)*16..+16
  // lane l -> row +(l>>2), col8 = (l&3)*8  (matches gload_lds linear lane x 16B)
  int seg0 = (w * 2 + 0) * 16;
  int seg1 = (w * 2 + 1) * 16;
  int srow0 = seg0 + (l >> 2);
  int srow1 = seg1 + (l >> 2);
  int scol  = (l & 3) * 8;

  const unsigned short* ga0 = A  + (R0 + srow0) * K + scol;
  const unsigned short* ga1 = A  + (R0 + srow1) * K + scol;
  const unsigned short* gb0 = BT + (size_t)(C0 + srow0) * K + scol;
  const unsigned short* gb1 = BT + (size_t)(C0 + srow1) * K + scol;

  f32x4 acc[4][4];
  #pragma unroll
  for (int i = 0; i < 4; ++i)
    #pragma unroll
    for (int j = 0; j < 4; ++j) acc[i][j] = (f32x4){0.f, 0.f, 0.f, 0.f};

  // prologue: stage tile 0 into buffer 0
  GLDS16(ga0, &As[0][seg0][0]);
  GLDS16(ga1, &As[0][seg1][0]);
  GLDS16(gb0, &Bs[0][seg0][0]);
  GLDS16(gb1, &Bs[0][seg1][0]);
  ga0 += 32; ga1 += 32; gb0 += 32; gb1 += 32;

  int nk = K >> 5;
  for (int t = 0; t < nk; ++t) {
    int cur = t & 1;
    __syncthreads();    // drains vmcnt(0): tile t resident; prior ds_reads retired
    if (t + 1 < nk) {   // issue next tile early; lands by next barrier
      GLDS16(ga0, &As[cur ^ 1][seg0][0]);
      GLDS16(ga1, &As[cur ^ 1][seg1][0]);
      GLDS16(gb0, &Bs[cur ^ 1][seg0][0]);
      GLDS16(gb1, &Bs[cur ^ 1][seg1][0]);
      ga0 += 32; ga1 += 32; gb0 += 32; gb1 += 32;
    }
    bf16x8 af[4], bf[4];
    #pragma unroll
    for (int mi = 0; mi < 4; ++mi)
      af[mi] = *(const bf16x8*)(&As[cur][wr*64 + mi*16 + (l & 15)][(l >> 4) * 8]);
    #pragma unroll
    for (int ni = 0; ni < 4; ++ni)
      bf[ni] = *(const bf16x8*)(&Bs[cur][wc*64 + ni*16 + (l & 15)][(l >> 4) * 8]);
    #pragma unroll
    for (int mi = 0; mi < 4; ++mi)
      #pragma unroll
      for (int ni = 0; ni < 4; ++ni)
        acc[mi][ni] = __builtin_amdgcn_mfma_f32_16x16x32_bf16(af[mi], bf[ni], acc[mi][ni], 0, 0, 0);
  }

  #pragma unroll
  for (int mi = 0; mi < 4; ++mi) {
    #pragma unroll
    for (int ni = 0; ni < 4; ++ni) {
      int col = C0 + wc*64 + ni*16 + (l & 15);
      #pragma unroll
      for (int j = 0; j < 4; ++j) {
        size_t row = R0 + wr*64 + mi*16 + ((l >> 4) << 2) + j;
        float vv = acc[mi][ni][j];
        if (EPI == 0) {
          ((unsigned short*)Cc)[row * Nn + col] = f2bf(vv);
        } else if (EPI == 1) {
          ((float*)Cc)[row * Nn + col] = vv + bias[col] + res[row * Nn + col];
        } else if (EPI == 2) {
          vv += bias[col];
          ((unsigned short*)Cc)[row * Nn + col] = f2bf(vv > 0.f ? vv : 0.f);
        } else {
          int buf = col / 384, c2 = col - buf * 384;   // buf uniform per block (128 | 384*k)
          ((unsigned short*)Cc)[(size_t)buf * NROW * 384 + row * 384 + c2] = f2bf(vv);
        }
      }
    }
  }
}

// ---------------- causal attention, one block per (b,h), T=128, DH=64 ----------------
// LDS union keeps static shared < 64 KB:
//   phase 1: Ks [128][72] (18432 B) at offset 0
//   phase 2: Ps [4][32][136] (34816 B) at offset 0   (K dead after QK^T; barrier in between)
//   always : Vt [64][136]  (17408 B) at offset 34816
// total 52224 B
__global__ __launch_bounds__(256) void attn_kernel(const unsigned short* __restrict__ q,
                                                   const unsigned short* __restrict__ k,
                                                   const unsigned short* __restrict__ v,
                                                   unsigned short* __restrict__ o) {
  __shared__ __align__(16) char smem[52224];
  unsigned short (*Ks)[72]       = (unsigned short(*)[72])smem;
  unsigned short (*Ps)[32][136]  = (unsigned short(*)[32][136])smem;
  unsigned short (*Vt)[136]      = (unsigned short(*)[136])(smem + 34816);

  int bh = blockIdx.x;
  int b = bh / H_, h = bh % H_;
  int tid = threadIdx.x, w = tid >> 6, l = tid & 63;

  const unsigned short* kb = k + ((size_t)b * T_) * D_ + h * DH_;
  const unsigned short* vb = v + ((size_t)b * T_) * D_ + h * DH_;
  #pragma unroll
  for (int it = 0; it < 4; ++it) {
    int id = it * 256 + tid;
    int s = id >> 3, c8 = (id & 7) * 8;
    int4 kv = *(const int4*)(kb + (size_t)s * D_ + c8);
    *(int4*)(&Ks[s][c8]) = kv;
    int4 vv = *(const int4*)(vb + (size_t)s * D_ + c8);
    const unsigned short* pe = (const unsigned short*)&vv;
    #pragma unroll
    for (int j2 = 0; j2 < 8; ++j2) Vt[c8 + j2][s] = pe[j2];
  }
  __syncthreads();

  // Q fragments straight from global (each wave owns rows w*32..w*32+31)
  const unsigned short* qbp = q + ((size_t)b * T_) * D_ + h * DH_;
  int rowbase = w * 32;
  bf16x8 aq[2][2];
  #pragma unroll
  for (int mi = 0; mi < 2; ++mi)
    #pragma unroll
    for (int ks = 0; ks < 2; ++ks)
      aq[mi][ks] = *(const bf16x8*)(qbp + (size_t)(rowbase + mi*16 + (l & 15)) * D_
                                        + ks*32 + ((l >> 4) << 3));

  // S = Q K^T  (wave strip: 32 x 128)
  f32x4 accs[2][8];
  #pragma unroll
  for (int i = 0; i < 2; ++i)
    #pragma unroll
    for (int j = 0; j < 8; ++j) accs[i][j] = (f32x4){0.f, 0.f, 0.f, 0.f};
  #pragma unroll
  for (int ks = 0; ks < 2; ++ks) {
    bf16x8 bk[8];
    #pragma unroll
    for (int ni = 0; ni < 8; ++ni)
      bk[ni] = *(const bf16x8*)(&Ks[ni*16 + (l & 15)][ks*32 + ((l >> 4) << 3)]);
    #pragma unroll
    for (int mi = 0; mi < 2; ++mi)
      #pragma unroll
      for (int ni = 0; ni < 8; ++ni)
        accs[mi][ni] = __builtin_amdgcn_mfma_f32_16x16x32_bf16(aq[mi][ks], bk[ni], accs[mi][ni], 0, 0, 0);
  }
  __syncthreads();   // all waves done reading Ks before P overwrites it

  // causal mask + row softmax (full row lives in 16 lanes x 8 ni-regs)
  #pragma unroll
  for (int mi = 0; mi < 2; ++mi) {
    #pragma unroll
    for (int j = 0; j < 4; ++j) {
      int t = rowbase + mi*16 + ((l >> 4) << 2) + j;
      float mx = -1e30f;
      #pragma unroll
      for (int ni = 0; ni < 8; ++ni) {
        int scol = ni*16 + (l & 15);
        float sv = accs[mi][ni][j] * 0.125f;
        sv = (scol <= t) ? sv : -1e30f;
        accs[mi][ni][j] = sv;
        mx = fmaxf(mx, sv);
      }
      mx = fmaxf(mx, __shfl_xor(mx, 1));
      mx = fmaxf(mx, __shfl_xor(mx, 2));
      mx = fmaxf(mx, __shfl_xor(mx, 4));
      mx = fmaxf(mx, __shfl_xor(mx, 8));
      float sum = 0.f;
      #pragma unroll
      for (int ni = 0; ni < 8; ++ni) {
        float e = __expf(accs[mi][ni][j] - mx);
        accs[mi][ni][j] = e;
        sum += e;
      }
      sum += __shfl_xor(sum, 1);
      sum += __shfl_xor(sum, 2);
      sum += __shfl_xor(sum, 4);
      sum += __shfl_xor(sum, 8);
      float inv = 1.f / sum;
      #pragma unroll
      for (int ni = 0; ni < 8; ++ni)
        Ps[w][mi*16 + ((l >> 4) << 2) + j][ni*16 + (l & 15)] = f2bf(accs[mi][ni][j] * inv);
    }
  }
  __syncthreads();

  // O = P V   (NT against Vt)
  f32x4 acco[2][4];
  #pragma unroll
  for (int i = 0; i < 2; ++i)
    #pragma unroll
    for (int j = 0; j < 4; ++j) acco[i][j] = (f32x4){0.f, 0.f, 0.f, 0.f};
  #pragma unroll
  for (int ks = 0; ks < 4; ++ks) {
    bf16x8 ap[2], bv[4];
    #pragma unroll
    for (int mi = 0; mi < 2; ++mi)
      ap[mi] = *(const bf16x8*)(&Ps[w][mi*16 + (l & 15)][ks*32 + ((l >> 4) << 3)]);
    #pragma unroll
    for (int ni = 0; ni < 4; ++ni)
      bv[ni] = *(const bf16x8*)(&Vt[ni*16 + (l & 15)][ks*32 + ((l >> 4) << 3)]);
    #pragma unroll
    for (int mi = 0; mi < 2; ++mi)
      #pragma unroll
      for (int ni = 0; ni < 4; ++ni)
        acco[mi][ni] = __builtin_amdgcn_mfma_f32_16x16x32_bf16(ap[mi], bv[ni], acco[mi][ni], 0, 0, 0);
  }

  unsigned short* ob = o + ((size_t)b * T_) * D_ + h * DH_;
  #pragma unroll
  for (int mi = 0; mi < 2; ++mi)
    #pragma unroll
    for (int ni = 0; ni < 4; ++ni)
      #pragma unroll
      for (int j = 0; j < 4; ++j) {
        int t = rowbase + mi*16 + ((l >> 4) << 2) + j;
        int d = ni*16 + (l & 15);
        ob[(size_t)t * D_ + d] = f2bf(acco[mi][ni][j]);
      }
}

extern "C" void kernel_launch(void* const* d_in, const int* in_sizes, int n_in,
                              void* d_out, int out_size, void* d_ws, size_t ws_size,
                              hipStream_t stream) {
  const float* x   = (const float*)d_in[0];
  const float* Wq  = (const float*)d_in[1];
  const float* Wk  = (const float*)d_in[2];
  const float* Wv  = (const float*)d_in[3];
  const float* Wo  = (const float*)d_in[4];
  const float* bo  = (const float*)d_in[5];
  const float* W1  = (const float*)d_in[6];
  const float* b1  = (const float*)d_in[7];
  const float* W2  = (const float*)d_in[8];
  const float* b2  = (const float*)d_in[9];
  const float* g1  = (const float*)d_in[10];
  const float* be1 = (const float*)d_in[11];
  const float* g2  = (const float*)d_in[12];
  const float* be2 = (const float*)d_in[13];

  // workspace layout (bytes); total ~195 MiB
  //   hb   [65536][384]  bf16  50,331,648  : h (LN1 out), later h2 (LN2 out)
  //   qb   [65536][384]  bf16  50,331,648  : q, overwritten in-place by attention output o
  //   kbuf [65536][384]  bf16  50,331,648  : k; dead after attn -> ff chunk buffer (with vbuf)
  //   vbuf [65536][384]  bf16  50,331,648  : v; dead after attn
  //   weights (bf16 transposed, contiguous: wq|wk|wv forms [1152][384])
  // x2 (fp32 residual stream) lives in d_out.
  char* ws = (char*)d_ws;
  unsigned short* hb   = (unsigned short*)(ws);
  unsigned short* qb   = (unsigned short*)(ws +  50331648);   // q|k|v contiguous
  unsigned short* kbuf = (unsigned short*)(ws + 100663296);
  unsigned short* vbuf = (unsigned short*)(ws + 150994944);
  unsigned short* ffb  = kbuf;   // [32768][1536] bf16 = 100,663,296 B spans kbuf+vbuf
  unsigned short* wqT  = (unsigned short*)(ws + 201326592);
  unsigned short* wkT  = wqT + 147456;
  unsigned short* wvT  = wkT + 147456;
  unsigned short* woT  = wvT + 147456;
  unsigned short* w1T  = woT + 147456;                       // [1536][384]
  unsigned short* w2T  = w1T + 589824;                       // [384][1536]
  float* x2 = (float*)d_out;

  // 1) weight convert+transpose (tiny)
  wt_kernel<<<dim3((384*384 + 255) / 256), 256, 0, stream>>>(Wq, wqT, 384, 384);
  wt_kernel<<<dim3((384*384 + 255) / 256), 256, 0, stream>>>(Wk, wkT, 384, 384);
  wt_kernel<<<dim3((384*384 + 255) / 256), 256, 0, stream>>>(Wv, wvT, 384, 384);
  wt_kernel<<<dim3((384*384 + 255) / 256), 256, 0, stream>>>(Wo, woT, 384, 384);
  wt_kernel<<<dim3((384*1536 + 255) / 256), 256, 0, stream>>>(W1, w1T, 384, 1536);
  wt_kernel<<<dim3((1536*384 + 255) / 256), 256, 0, stream>>>(W2, w2T, 1536, 384);

  // 2) LN1: x -> h (bf16)
  ln_kernel<<<dim3(NROW / 4), 256, 0, stream>>>(x, g1, be1, hb);

  // 3) fused q|k|v = h @ [Wq|Wk|Wv]  (N=1152, split-store epilogue)
  gemm_bt<3><<<dim3(NROW / 128, 9), 256, 0, stream>>>(hb, wqT, qb, nullptr, nullptr, 1152, 384);

  // 4) attention: o overwrites q in place (per-block disjoint strips)
  attn_kernel<<<dim3(B_ * H_), 256, 0, stream>>>(qb, kbuf, vbuf, qb);

  // 5) x2 = x + o @ Wo + bo   (fp32, into d_out)
  gemm_bt<1><<<dim3(NROW / 128, 3), 256, 0, stream>>>(qb, woT, x2, bo, x, 384, 384);

  // 6) LN2: x2 -> h2 (bf16, into hb)
  ln_kernel<<<dim3(NROW / 4), 256, 0, stream>>>((const float*)x2, g2, be2, hb);

  // 7) FFN in 2 row-chunks of 32768 (ffb reuses dead k/v region)
  for (int c = 0; c < 2; ++c) {
    const unsigned short* h2c = hb + (size_t)c * 32768 * 384;
    float* outc = x2 + (size_t)c * 32768 * 384;
    gemm_bt<2><<<dim3(256, 12), 256, 0, stream>>>(h2c, w1T, ffb, b1, nullptr, 1536, 384);
    gemm_bt<1><<<dim3(256, 3),  256, 0, stream>>>(ffb, w2T, outc, b2, outc, 384, 1536);
  }
}